// Round 12
// baseline (227.401 us; speedup 1.0000x reference)
//
#include <hip/hip_runtime.h>
#include <hip/hip_bf16.h>
#include <hip/hip_fp16.h>

#define Bc 8
#define Nc 256
#define Dc 256
#define Hc 16
#define DKc 16
#define MSc 16
#define FFc 512
#define SZc 524288          // B*N*D elements
#define WHALF 524288        // bf16 elems of one half's 6 transposed weights
#define FFH 1048576         // B*N*FF elements

typedef __hip_bfloat16 bf16;
typedef __attribute__((ext_vector_type(8))) short bfrag8;   // 8 bf16 (4 VGPR)
typedef __attribute__((ext_vector_type(4))) float f32x4;    // MFMA acc

__device__ __forceinline__ short f2bs(float x) {
    bf16 t = __float2bfloat16(x);
    return *reinterpret_cast<short*>(&t);
}

__device__ __forceinline__ short f2hs(float x) {
    __half t = __float2half(x);
    return *reinterpret_cast<short*>(&t);
}

// packed fp16 ReLU: no __half2 __hmax2 in ROCm 7.2 fp16 header; one VOP3P
// instruction, single 32-bit VGPR in/out (no pair-alignment pressure).
__device__ __forceinline__ __half2 pk_relu(__half2 x) {
    __half2 r;
    asm("v_pk_max_f16 %0, %1, 0" : "=v"(r) : "v"(x));
    return r;
}

// ---------------------------------------------------------------------------
// Dispatch 1: setup. grid (256, 18), block 256. (unchanged from R11)
// ---------------------------------------------------------------------------
__global__ void setup_kernel(const float* __restrict__ e0, const float* __restrict__ e1,
                             bf16* __restrict__ o0, bf16* __restrict__ o1,
                             float* __restrict__ statsB,
                             const float* __restrict__ cost,
                             short* __restrict__ costH, short* __restrict__ costHT,
                             const float* rWq, const float* rWk, const float* rWv,
                             const float* rcw, const float* rw1, const float* rw2,
                             const float* cWq, const float* cWk, const float* cWv,
                             const float* ccw, const float* cw1, const float* cw2,
                             const float* rm1w, const float* rm1b, const float* rm2w,
                             const float* cm1w, const float* cm1b, const float* cm2w,
                             __half2* __restrict__ Wpk,
                             bf16* __restrict__ WT) {
    int y = blockIdx.y;
    if (y < 2) {
        const float* src = y ? e1 : e0;
        bf16* dst = y ? o1 : o0;
        size_t base = (size_t)blockIdx.x * 2048 + threadIdx.x;
#pragma unroll
        for (int i = 0; i < 8; ++i)
            dst[base + i * 256] = __float2bfloat16(src[base + i * 256]);
        return;
    }
    if (y == 2) {
        if (blockIdx.x < 64) {
            statsB[blockIdx.x * 256 + threadIdx.x] = 0.f;
        } else if (blockIdx.x < 66) {
            int p = blockIdx.x - 64;
            const float* m1w = p ? cm1w : rm1w;
            const float* m1b = p ? cm1b : rm1b;
            const float* m2w = p ? cm2w : rm2w;
            int h = threadIdx.x >> 4, m = threadIdx.x & 15;
            __half2* wp = Wpk + (size_t)(p * 16 + h) * 64;
            wp[m]      = __float2half2_rn(m1w[h * 32 + m] * 0.25f);  // dot-scale folded
            wp[16 + m] = __float2half2_rn(m1w[h * 32 + 16 + m]);
            wp[32 + m] = __float2half2_rn(m1b[h * 16 + m]);
            wp[48 + m] = __float2half2_rn(m2w[h * 16 + m]);
        }
        return;
    }
    if (y == 15) {
        size_t base = (size_t)blockIdx.x * 2048 + threadIdx.x;
#pragma unroll
        for (int i = 0; i < 8; ++i)
            costH[base + i * 256] = f2hs(cost[base + i * 256]);
        return;
    }
    __shared__ float t[32][33];
    int tx = threadIdx.x & 31, ty = threadIdx.x >> 5;   // 32 x 8
    if (y >= 16) {
        int tl = blockIdx.x + (y - 16) * 256;           // 0..511
        int bb = tl >> 6, t2 = tl & 63;
        int r0 = (t2 >> 3) * 32, c0 = (t2 & 7) * 32;
        const float* src = cost + (size_t)bb * 65536;
        short* dst = costHT + (size_t)bb * 65536;
#pragma unroll
        for (int i = 0; i < 4; ++i)
            t[ty + i * 8][tx] = src[(size_t)(r0 + ty + i * 8) * 256 + c0 + tx];
        __syncthreads();
#pragma unroll
        for (int i = 0; i < 4; ++i)
            dst[(size_t)(c0 + ty + i * 8) * 256 + r0 + tx] = f2hs(t[tx][ty + i * 8]);
        return;
    }
    int z = y - 3;                    // 0..11
    int p = z / 6, widx = z % 6;
    const float* src; int K, N; size_t off;
    switch (widx) {
        case 0: src = p ? cWq : rWq; K = 256; N = 256; off = 0; break;
        case 1: src = p ? cWk : rWk; K = 256; N = 256; off = 65536; break;
        case 2: src = p ? cWv : rWv; K = 256; N = 256; off = 131072; break;
        case 3: src = p ? ccw : rcw; K = 256; N = 256; off = 196608; break;
        case 4: src = p ? cw1 : rw1; K = 256; N = 512; off = 262144; break;
        default: src = p ? cw2 : rw2; K = 512; N = 256; off = 393216; break;
    }
    int Ntiles = N >> 5, Ktiles = K >> 5;
    if ((int)blockIdx.x >= Ktiles * Ntiles) return;
    int kt = blockIdx.x / Ntiles, nt = blockIdx.x - kt * Ntiles;
    int k0 = kt * 32, n0 = nt * 32;
    bf16* dst = WT + (size_t)p * WHALF + off;
#pragma unroll
    for (int i = 0; i < 4; ++i)
        t[ty + i * 8][tx] = src[(size_t)(k0 + ty + i * 8) * N + n0 + tx];
    __syncthreads();
#pragma unroll
    for (int i = 0; i < 4; ++i)
        dst[(size_t)(n0 + ty + i * 8) * K + k0 + tx] = __float2bfloat16(t[tx][ty + i * 8]);
}

// ---------------------------------------------------------------------------
// Stage bodies as __device__ functions (R12: skewed half-pipeline).
// Virtual block coords passed explicitly; p selects half.
// ---------------------------------------------------------------------------
__device__ __forceinline__ void qkv_body(int p, int j, int vbx, int vby,
        const short* __restrict__ embRb, const short* __restrict__ embCb,
        const short* __restrict__ WT, bf16* __restrict__ qkv) {
    const short* A  = (j == 0) ? (p ? embCb : embRb) : (p ? embRb : embCb);
    const short* BT = WT + (size_t)p * WHALF + j * 65536;
    bf16* out = qkv + (size_t)(p * 3 + j) * SZc;

    int lane = threadIdx.x & 63, w = threadIdx.x >> 6;
    int m_base = vbx * 64 + (w & 1) * 32;
    int n_base = vby * 64 + (w >> 1) * 32;
    int mr = lane & 15, quad = lane >> 4;

    const short* pa0 = A + (size_t)(m_base + mr) * 256 + quad * 8;
    const short* pa1 = pa0 + 16 * 256;
    const short* pb0 = BT + (size_t)(n_base + mr) * 256 + quad * 8;
    const short* pb1 = pb0 + 16 * 256;

    f32x4 acc00 = {0.f, 0.f, 0.f, 0.f}, acc01 = {0.f, 0.f, 0.f, 0.f};
    f32x4 acc10 = {0.f, 0.f, 0.f, 0.f}, acc11 = {0.f, 0.f, 0.f, 0.f};
#pragma unroll
    for (int kt = 0; kt < 256; kt += 32) {
        bfrag8 A0 = *(const bfrag8*)(pa0 + kt);
        bfrag8 A1 = *(const bfrag8*)(pa1 + kt);
        bfrag8 B0 = *(const bfrag8*)(pb0 + kt);
        bfrag8 B1 = *(const bfrag8*)(pb1 + kt);
        acc00 = __builtin_amdgcn_mfma_f32_16x16x32_bf16(A0, B0, acc00, 0, 0, 0);
        acc01 = __builtin_amdgcn_mfma_f32_16x16x32_bf16(A0, B1, acc01, 0, 0, 0);
        acc10 = __builtin_amdgcn_mfma_f32_16x16x32_bf16(A1, B0, acc10, 0, 0, 0);
        acc11 = __builtin_amdgcn_mfma_f32_16x16x32_bf16(A1, B1, acc11, 0, 0, 0);
    }

#pragma unroll
    for (int jt = 0; jt < 2; ++jt) {
        int col = n_base + jt * 16 + mr;
        int h = col >> 4, dk = col & 15;
        f32x4 a0 = jt ? acc01 : acc00;
        f32x4 a1 = jt ? acc11 : acc10;
#pragma unroll
        for (int r = 0; r < 4; ++r) {
            int row0 = m_base + quad * 4 + r;
            int row1 = row0 + 16;
            int b0 = row0 >> 8, n0 = row0 & 255;
            int b1 = row1 >> 8, n1 = row1 & 255;
            out[((size_t)(b0 * Hc + h) * Nc + n0) * DKc + dk] = __float2bfloat16(a0[r]);
            out[((size_t)(b1 * Hc + h) * Nc + n1) * DKc + dk] = __float2bfloat16(a1[r]);
        }
    }
}

// smem layout: sVT @0 (8448B), sEb @8448 (8448B), sPart @16896 (4096B),
// sSum @20992 (256B) -> 21248B total.
#define ATTN_SMEM 21504
__device__ __forceinline__ void attn_body(int p, int b, int h, int rc, char* smem,
        const short* __restrict__ qkv,
        const short* __restrict__ costH, const short* __restrict__ costHT,
        const __half2* __restrict__ Wpk,
        const float* rm2b, const float* cm2b, bf16* __restrict__ attnb) {
    short* sVT  = (short*)smem;
    short* sEb  = (short*)(smem + 8448);
    float* sPart = (float*)(smem + 16896);
    float* sSum  = (float*)(smem + 20992);

    const short* Q = qkv + (size_t)(p * 3 + 0) * SZc;
    const short* K = qkv + (size_t)(p * 3 + 1) * SZc;
    const short* V = qkv + (size_t)(p * 3 + 2) * SZc;
    const __half2* wp = Wpk + (size_t)(p * 16 + h) * 64;
    float b2v = (p ? cm2b : rm2b)[h];
    bf16* out_concat = attnb + (size_t)p * SZc;

    int bh = b * Hc + h;
    int r0 = rc * 16;
    int c = threadIdx.x;
    int lane = c & 63, wid = c >> 6;
    int mr = lane & 15, quad = lane >> 4;

    // V staging: thread c owns V row c (col c of V^T) — already bf16
    {
        const short* vp = V + ((size_t)bh * Nc + c) * DKc;
        bfrag8 v0 = *(const bfrag8*)vp;
        bfrag8 v1 = *(const bfrag8*)(vp + 8);
#pragma unroll
        for (int i = 0; i < 8; ++i) {
            sVT[i * 264 + c]       = v0[i];
            sVT[(8 + i) * 264 + c] = v1[i];
        }
    }

    bfrag8 qf = {0, 0, 0, 0, 0, 0, 0, 0};
    if (quad < 2)
        qf = *(const bfrag8*)(Q + ((size_t)bh * Nc + r0 + mr) * DKc + quad * 8);

    __half2 sv2[8];
#pragma unroll
    for (int t = 0; t < 4; ++t) {
        bfrag8 kf = {0, 0, 0, 0, 0, 0, 0, 0};
        if (quad < 2)
            kf = *(const bfrag8*)(K + ((size_t)bh * Nc + wid * 64 + t * 16 + mr) * DKc + quad * 8);
        f32x4 acc = {0.f, 0.f, 0.f, 0.f};
        acc = __builtin_amdgcn_mfma_f32_16x16x32_bf16(qf, kf, acc, 0, 0, 0);
        sv2[t * 2]     = __floats2half2_rn(acc[0], acc[1]);
        sv2[t * 2 + 1] = __floats2half2_rn(acc[2], acc[3]);
    }

    const __half2* cp = (const __half2*)((p ? costH : costHT) + (size_t)b * 65536);
    __half2 cv2[8];
#pragma unroll
    for (int t = 0; t < 4; ++t) {
        int col = wid * 64 + t * 16 + mr;
        int h2i = (col << 7) + (r0 >> 1) + (quad << 1);
        uint2 u = *(const uint2*)(cp + h2i);
        cv2[t * 2]     = *reinterpret_cast<__half2*>(&u.x);
        cv2[t * 2 + 1] = *reinterpret_cast<__half2*>(&u.y);
    }

    __syncthreads();   // sVT staged

    const __half2 z2 = __half2half2(__float2half(0.f));
    __half2 mix2[8] = {z2, z2, z2, z2, z2, z2, z2, z2};
#pragma unroll
    for (int m = 0; m < MSc; ++m) {
        __half2 w1d = wp[m];
        __half2 w1c = wp[16 + m];
        __half2 b1v = wp[32 + m];
        __half2 w2v = wp[48 + m];
#pragma unroll
        for (int s = 0; s < 8; ++s) {
            __half2 tt = __hfma2(sv2[s], w1d, __hfma2(cv2[s], w1c, b1v));
            mix2[s] = __hfma2(pk_relu(tt), w2v, mix2[s]);
        }
    }
    float ex[16];
#pragma unroll
    for (int s = 0; s < 8; ++s) {
        float2 mf = __half22float2(mix2[s]);
        ex[s * 2]     = __expf(mf.x + b2v);
        ex[s * 2 + 1] = __expf(mf.y + b2v);
    }

#pragma unroll
    for (int t = 0; t < 4; ++t)
#pragma unroll
        for (int r = 0; r < 4; ++r)
            sEb[(quad * 4 + r) * 264 + wid * 64 + t * 16 + mr] = f2bs(ex[t * 4 + r]);

#pragma unroll
    for (int r = 0; r < 4; ++r) {
        float rp = ex[r] + ex[4 + r] + ex[8 + r] + ex[12 + r];
        rp += __shfl_xor(rp, 1);
        rp += __shfl_xor(rp, 2);
        rp += __shfl_xor(rp, 4);
        rp += __shfl_xor(rp, 8);
        if (mr == 0) sSum[(quad * 4 + r) * 4 + wid] = rp;
    }
    __syncthreads();

    {
        const short* pa = &sEb[mr * 264 + wid * 64 + quad * 8];
        const short* pb = &sVT[mr * 264 + wid * 64 + quad * 8];
        f32x4 acc = {0.f, 0.f, 0.f, 0.f};
        bfrag8 a0 = *(const bfrag8*)pa;
        bfrag8 b0 = *(const bfrag8*)pb;
        acc = __builtin_amdgcn_mfma_f32_16x16x32_bf16(a0, b0, acc, 0, 0, 0);
        bfrag8 a1 = *(const bfrag8*)(pa + 32);
        bfrag8 b1 = *(const bfrag8*)(pb + 32);
        acc = __builtin_amdgcn_mfma_f32_16x16x32_bf16(a1, b1, acc, 0, 0, 0);
#pragma unroll
        for (int r = 0; r < 4; ++r)
            sPart[wid * 256 + (quad * 4 + r) * 16 + mr] = acc[r];
    }
    __syncthreads();

    {
        int r = c >> 4, dk = c & 15;
        float o = sPart[c] + sPart[256 + c] + sPart[512 + c] + sPart[768 + c];
        float sum = sSum[r * 4] + sSum[r * 4 + 1] + sSum[r * 4 + 2] + sSum[r * 4 + 3];
        out_concat[((size_t)(b * Nc + r0 + r)) * Dc + h * DKc + dk] =
            __float2bfloat16(o / sum);
    }
}

__device__ __forceinline__ void cat_body(int p, int vbx, int vby,
        const short* __restrict__ attnb, const short* __restrict__ WT,
        const float* rcb, const float* ccb,
        const float* __restrict__ resR, const float* __restrict__ resC,
        float* __restrict__ x1, float* __restrict__ stats1) {
    const short* A  = attnb + (size_t)p * SZc;
    const short* BT = WT + (size_t)p * WHALF + 196608;
    const float* bias = p ? ccb : rcb;
    const float* res  = p ? resC : resR;
    float* outF = x1 + (size_t)p * SZc;
    float* st   = stats1 + p * 4096;

    int lane = threadIdx.x & 63, w = threadIdx.x >> 6;
    int m_base = vbx * 64 + (w & 1) * 32;
    int n_base = vby * 64 + (w >> 1) * 32;
    int mr = lane & 15, quad = lane >> 4;

    const short* pa0 = A + (size_t)(m_base + mr) * 256 + quad * 8;
    const short* pa1 = pa0 + (size_t)16 * 256;
    const short* pb0 = BT + (size_t)(n_base + mr) * 256 + quad * 8;
    const short* pb1 = pb0 + (size_t)16 * 256;

    f32x4 acc00 = {0.f, 0.f, 0.f, 0.f}, acc01 = {0.f, 0.f, 0.f, 0.f};
    f32x4 acc10 = {0.f, 0.f, 0.f, 0.f}, acc11 = {0.f, 0.f, 0.f, 0.f};
#pragma unroll
    for (int kt = 0; kt < 256; kt += 32) {
        bfrag8 A0 = *(const bfrag8*)(pa0 + kt);
        bfrag8 A1 = *(const bfrag8*)(pa1 + kt);
        bfrag8 B0 = *(const bfrag8*)(pb0 + kt);
        bfrag8 B1 = *(const bfrag8*)(pb1 + kt);
        acc00 = __builtin_amdgcn_mfma_f32_16x16x32_bf16(A0, B0, acc00, 0, 0, 0);
        acc01 = __builtin_amdgcn_mfma_f32_16x16x32_bf16(A0, B1, acc01, 0, 0, 0);
        acc10 = __builtin_amdgcn_mfma_f32_16x16x32_bf16(A1, B0, acc10, 0, 0, 0);
        acc11 = __builtin_amdgcn_mfma_f32_16x16x32_bf16(A1, B1, acc11, 0, 0, 0);
    }

    int bb = m_base >> 8;
#pragma unroll
    for (int jt = 0; jt < 2; ++jt) {
        int col = n_base + jt * 16 + mr;
        float bv = bias[col];
        f32x4 a0 = jt ? acc01 : acc00;
        f32x4 a1 = jt ? acc11 : acc10;
        float ssum = 0.f, ssq = 0.f;
#pragma unroll
        for (int r = 0; r < 4; ++r) {
            int row0 = m_base + quad * 4 + r;
            int row1 = row0 + 16;
            float v0 = a0[r] + bv + res[(size_t)row0 * 256 + col];
            float v1 = a1[r] + bv + res[(size_t)row1 * 256 + col];
            outF[(size_t)row0 * 256 + col] = v0;
            outF[(size_t)row1 * 256 + col] = v1;
            ssum += v0 + v1;
            ssq  += v0 * v0 + v1 * v1;
        }
        atomicAdd(&st[(bb * 256 + col) * 2],     ssum);
        atomicAdd(&st[(bb * 256 + col) * 2 + 1], ssq);
    }
}

#define FF1N_SMEM 33792   // short sA[64*264]
__device__ __forceinline__ void ff1n_body(int p, int vbx, int vby, char* smem,
        const float* __restrict__ x1, const float* __restrict__ stats1,
        const float* rn1s, const float* rn1b, const float* cn1s, const float* cn1b,
        const short* __restrict__ WT, const float* rb1, const float* cb1,
        bf16* __restrict__ ffh) {
    short* sA = (short*)smem;
    const float* X   = x1 + (size_t)p * SZc;
    const float* st  = stats1 + p * 4096;
    const float* n1s = p ? cn1s : rn1s;
    const float* n1b = p ? cn1b : rn1b;
    const short* BT  = WT + (size_t)p * WHALF + 262144;
    const float* bias = p ? cb1 : rb1;
    bf16* outB = ffh + (size_t)p * FFH;

    int c = threadIdx.x;
    int m_base = vbx * 64;
    int b = m_base >> 8;

    float s = st[(b * 256 + c) * 2];
    float q = st[(b * 256 + c) * 2 + 1];
    float mean = s * (1.f / Nc);
    float var = q * (1.f / Nc) - mean * mean;
    float inv = rsqrtf(var + 1e-5f) * n1s[c];
    float nb = n1b[c];
#pragma unroll 8
    for (int i = 0; i < 64; ++i) {
        float v = X[(size_t)(m_base + i) * 256 + c];
        sA[i * 264 + c] = f2bs((v - mean) * inv + nb);
    }
    __syncthreads();

    int lane = c & 63, w = c >> 6;
    int mloc = (w & 1) * 32;
    int n_base = vby * 64 + (w >> 1) * 32;
    int mr = lane & 15, quad = lane >> 4;

    const short* pa0 = &sA[(mloc + mr) * 264 + quad * 8];
    const short* pa1 = pa0 + 16 * 264;
    const short* pb0 = BT + (size_t)(n_base + mr) * 256 + quad * 8;
    const short* pb1 = pb0 + 16 * 256;

    f32x4 acc00 = {0.f, 0.f, 0.f, 0.f}, acc01 = {0.f, 0.f, 0.f, 0.f};
    f32x4 acc10 = {0.f, 0.f, 0.f, 0.f}, acc11 = {0.f, 0.f, 0.f, 0.f};
#pragma unroll
    for (int kt = 0; kt < 256; kt += 32) {
        bfrag8 A0 = *(const bfrag8*)(pa0 + kt);
        bfrag8 A1 = *(const bfrag8*)(pa1 + kt);
        bfrag8 B0 = *(const bfrag8*)(pb0 + kt);
        bfrag8 B1 = *(const bfrag8*)(pb1 + kt);
        acc00 = __builtin_amdgcn_mfma_f32_16x16x32_bf16(A0, B0, acc00, 0, 0, 0);
        acc01 = __builtin_amdgcn_mfma_f32_16x16x32_bf16(A0, B1, acc01, 0, 0, 0);
        acc10 = __builtin_amdgcn_mfma_f32_16x16x32_bf16(A1, B0, acc10, 0, 0, 0);
        acc11 = __builtin_amdgcn_mfma_f32_16x16x32_bf16(A1, B1, acc11, 0, 0, 0);
    }

#pragma unroll
    for (int jt = 0; jt < 2; ++jt) {
        int col = n_base + jt * 16 + mr;
        float bv = bias[col];
        f32x4 a0 = jt ? acc01 : acc00;
        f32x4 a1 = jt ? acc11 : acc10;
#pragma unroll
        for (int r = 0; r < 4; ++r) {
            int row0 = m_base + mloc + quad * 4 + r;
            int row1 = row0 + 16;
            outB[(size_t)row0 * 512 + col] = __float2bfloat16(fmaxf(a0[r] + bv, 0.f));
            outB[(size_t)row1 * 512 + col] = __float2bfloat16(fmaxf(a1[r] + bv, 0.f));
        }
    }
}

__device__ __forceinline__ void ff2n_body(int p, int vbx, int vby,
        const short* __restrict__ ffh, const short* __restrict__ WT,
        const float* rb2, const float* cb2,
        const float* __restrict__ x1, const float* __restrict__ stats1,
        const float* rn1s, const float* rn1b,
        const float* cn1s, const float* cn1b,
        float* __restrict__ ff2, float* __restrict__ stats2) {
    const short* A  = ffh + (size_t)p * FFH;
    const short* BT = WT + (size_t)p * WHALF + 393216;
    const float* bias = p ? cb2 : rb2;
    const float* X   = x1 + (size_t)p * SZc;
    const float* st1 = stats1 + p * 4096;
    const float* n1s = p ? cn1s : rn1s;
    const float* n1b = p ? cn1b : rn1b;
    float* outF = ff2 + (size_t)p * SZc;
    float* st2  = stats2 + p * 4096;

    int lane = threadIdx.x & 63, w = threadIdx.x >> 6;
    int m_base = vbx * 64 + (w & 1) * 32;
    int n_base = vby * 64 + (w >> 1) * 32;
    int mr = lane & 15, quad = lane >> 4;

    const short* pa0 = A + (size_t)(m_base + mr) * 512 + quad * 8;
    const short* pa1 = pa0 + (size_t)16 * 512;
    const short* pb0 = BT + (size_t)(n_base + mr) * 512 + quad * 8;
    const short* pb1 = pb0 + (size_t)16 * 512;

    f32x4 acc00 = {0.f, 0.f, 0.f, 0.f}, acc01 = {0.f, 0.f, 0.f, 0.f};
    f32x4 acc10 = {0.f, 0.f, 0.f, 0.f}, acc11 = {0.f, 0.f, 0.f, 0.f};
#pragma unroll
    for (int kt = 0; kt < 512; kt += 32) {
        bfrag8 A0 = *(const bfrag8*)(pa0 + kt);
        bfrag8 A1 = *(const bfrag8*)(pa1 + kt);
        bfrag8 B0 = *(const bfrag8*)(pb0 + kt);
        bfrag8 B1 = *(const bfrag8*)(pb1 + kt);
        acc00 = __builtin_amdgcn_mfma_f32_16x16x32_bf16(A0, B0, acc00, 0, 0, 0);
        acc01 = __builtin_amdgcn_mfma_f32_16x16x32_bf16(A0, B1, acc01, 0, 0, 0);
        acc10 = __builtin_amdgcn_mfma_f32_16x16x32_bf16(A1, B0, acc10, 0, 0, 0);
        acc11 = __builtin_amdgcn_mfma_f32_16x16x32_bf16(A1, B1, acc11, 0, 0, 0);
    }

    int bb = m_base >> 8;
#pragma unroll
    for (int jt = 0; jt < 2; ++jt) {
        int col = n_base + jt * 16 + mr;
        float s1 = st1[(bb * 256 + col) * 2];
        float q1 = st1[(bb * 256 + col) * 2 + 1];
        float mean1 = s1 * (1.f / Nc);
        float var1 = q1 * (1.f / Nc) - mean1 * mean1;
        float inv1 = rsqrtf(var1 + 1e-5f) * n1s[col];
        float nb1 = n1b[col];
        float bv = bias[col];
        f32x4 a0 = jt ? acc01 : acc00;
        f32x4 a1 = jt ? acc11 : acc10;
        float ssum = 0.f, ssq = 0.f;
#pragma unroll
        for (int r = 0; r < 4; ++r) {
            int row0 = m_base + quad * 4 + r;
            int row1 = row0 + 16;
            float res0 = (X[(size_t)row0 * 256 + col] - mean1) * inv1 + nb1;
            float res1 = (X[(size_t)row1 * 256 + col] - mean1) * inv1 + nb1;
            float v0 = a0[r] + bv + res0;
            float v1 = a1[r] + bv + res1;
            outF[(size_t)row0 * 256 + col] = v0;
            outF[(size_t)row1 * 256 + col] = v1;
            ssum += v0 + v1;
            ssq  += v0 * v0 + v1 * v1;
        }
        atomicAdd(&st2[(bb * 256 + col) * 2],     ssum);
        atomicAdd(&st2[(bb * 256 + col) * 2 + 1], ssq);
    }
}

__device__ __forceinline__ void apply_body(int p, int vb,
        const float* __restrict__ x, const float* __restrict__ stats,
        const float* sR, const float* bR,
        const float* sC, const float* bC,
        float* __restrict__ outF) {
    int t = threadIdx.x;
    int row = vb * 4 + (t >> 6);
    int d0 = (t & 63) * 4;
    int b = row >> 8;
    const float* st = stats + p * 4096 + (size_t)(b * 256 + d0) * 2;
    float4 s01 = *(const float4*)st;
    float4 s23 = *(const float4*)(st + 4);
    const float* sp = p ? sC : sR;
    const float* bp = p ? bC : bR;
    float4 sc = *(const float4*)(sp + d0);
    float4 bi = *(const float4*)(bp + d0);
    float4 v = *(const float4*)(x + (size_t)p * SZc + (size_t)row * Dc + d0);
    float sums[4] = {s01.x, s01.z, s23.x, s23.z};
    float sqs[4]  = {s01.y, s01.w, s23.y, s23.w};
    float vv[4]   = {v.x, v.y, v.z, v.w};
    float scs[4]  = {sc.x, sc.y, sc.z, sc.w};
    float bis[4]  = {bi.x, bi.y, bi.z, bi.w};
    float4 o;
#pragma unroll
    for (int j = 0; j < 4; ++j) {
        float mean = sums[j] * (1.f / Nc);
        float var = sqs[j] * (1.f / Nc) - mean * mean;
        float inv = rsqrtf(var + 1e-5f);
        ((float*)&o)[j] = (vv[j] - mean) * inv * scs[j] + bis[j];
    }
    *(float4*)(outF + (size_t)p * SZc + (size_t)row * Dc + d0) = o;
}

// ---------------------------------------------------------------------------
// Skewed-pipeline combined kernels. Block-range partition (no per-thread
// divergence). Longer stage placed first in the block range.
// ---------------------------------------------------------------------------
__global__ __launch_bounds__(256) void k_qkv0(
        const short* embRb, const short* embCb, const short* WT, bf16* qkv) {
    int vb = blockIdx.x;                  // 384
    qkv_body(0, vb >> 7, vb & 31, (vb >> 5) & 3, embRb, embCb, WT, qkv);
}

__global__ __launch_bounds__(256) void k_attn0_qkv1(
        const short* qkv, const short* costH, const short* costHT,
        const __half2* Wpk, const float* rm2b, const float* cm2b, bf16* attnb,
        const short* embRb, const short* embCb, const short* WT, bf16* qkvout) {
    __shared__ __align__(16) char smem[ATTN_SMEM];
    int vb = blockIdx.x;                  // 2048 + 384 = 2432
    if (vb < 2048)
        attn_body(0, vb & 7, (vb >> 3) & 15, vb >> 7, smem,
                  qkv, costH, costHT, Wpk, rm2b, cm2b, attnb);
    else {
        int u = vb - 2048;
        qkv_body(1, u >> 7, u & 31, (u >> 5) & 3, embRb, embCb, WT, qkvout);
    }
}

__global__ __launch_bounds__(256) void k_attn1_cat0(
        const short* qkv, const short* costH, const short* costHT,
        const __half2* Wpk, const float* rm2b, const float* cm2b, bf16* attnb,
        const short* WT, const float* rcb, const float* ccb,
        const float* resR, const float* resC, float* x1, float* stats1) {
    __shared__ __align__(16) char smem[ATTN_SMEM];
    int vb = blockIdx.x;                  // 2048 + 128 = 2176
    if (vb < 2048)
        attn_body(1, vb & 7, (vb >> 3) & 15, vb >> 7, smem,
                  qkv, costH, costHT, Wpk, rm2b, cm2b, attnb);
    else {
        int u = vb - 2048;
        cat_body(0, u & 31, u >> 5, (const short*)attnb, WT, rcb, ccb,
                 resR, resC, x1, stats1);
    }
}

__global__ __launch_bounds__(256) void k_ff1n0_cat1(
        const float* x1, const float* stats1,
        const float* rn1s, const float* rn1b, const float* cn1s, const float* cn1b,
        const short* WT, const float* rb1, const float* cb1, bf16* ffh,
        const short* attnb, const float* rcb, const float* ccb,
        const float* resR, const float* resC, float* x1out, float* stats1out) {
    __shared__ __align__(16) char smem[FF1N_SMEM];
    int vb = blockIdx.x;                  // 256 + 128 = 384
    if (vb < 256)
        ff1n_body(0, vb & 31, vb >> 5, smem, x1, stats1,
                  rn1s, rn1b, cn1s, cn1b, WT, rb1, cb1, ffh);
    else {
        int u = vb - 256;
        cat_body(1, u & 31, u >> 5, attnb, WT, rcb, ccb, resR, resC,
                 x1out, stats1out);
    }
}

__global__ __launch_bounds__(256) void k_ff2n0_ff1n1(
        const short* ffh, const short* WT, const float* rb2, const float* cb2,
        const float* x1, const float* stats1,
        const float* rn1s, const float* rn1b, const float* cn1s, const float* cn1b,
        float* ff2, float* stats2,
        const float* rb1, const float* cb1, bf16* ffhout) {
    __shared__ __align__(16) char smem[FF1N_SMEM];
    int vb = blockIdx.x;                  // 128 + 256 = 384
    if (vb < 128)
        ff2n_body(0, vb & 31, vb >> 5, ffh, WT, rb2, cb2, x1, stats1,
                  rn1s, rn1b, cn1s, cn1b, ff2, stats2);
    else {
        int u = vb - 128;
        ff1n_body(1, u & 31, u >> 5, smem, x1, stats1,
                  rn1s, rn1b, cn1s, cn1b, WT, rb1, cb1, ffhout);
    }
}

__global__ __launch_bounds__(256) void k_ff2n1_apply0(
        const short* ffh, const short* WT, const float* rb2, const float* cb2,
        const float* x1, const float* stats1,
        const float* rn1s, const float* rn1b, const float* cn1s, const float* cn1b,
        float* ff2, float* stats2,
        const float* n2sR, const float* n2bR, const float* n2sC, const float* n2bC,
        float* outF) {
    int vb = blockIdx.x;                  // 128 + 512 = 640
    if (vb < 128)
        ff2n_body(1, vb & 31, vb >> 5, ffh, WT, rb2, cb2, x1, stats1,
                  rn1s, rn1b, cn1s, cn1b, ff2, stats2);
    else
        apply_body(0, vb - 128, ff2, stats2, n2sR, n2bR, n2sC, n2bC, outF);
}

__global__ __launch_bounds__(256) void k_apply1(
        const float* ff2, const float* stats2,
        const float* n2sR, const float* n2bR, const float* n2sC, const float* n2bC,
        float* outF) {
    apply_body(1, blockIdx.x, ff2, stats2, n2sR, n2bR, n2sC, n2bC, outF);
}

extern "C" void kernel_launch(void* const* d_in, const int* in_sizes, int n_in,
                              void* d_out, int out_size, void* d_ws, size_t ws_size,
                              hipStream_t stream) {
    const float* row_emb = (const float*)d_in[0];
    const float* col_emb = (const float*)d_in[1];
    const float* cost    = (const float*)d_in[2];
    float* out = (float*)d_out;
    float* ws = (float*)d_ws;
    // per-half param index (dict order): 0 Wq, 1 Wk, 2 Wv, 3 m1w, 4 m1b,
    // 5 m2w, 6 m2b, 7 cw, 8 cb, 9 n1s, 10 n1b, 11 w1, 12 b1, 13 w2, 14 b2,
    // 15 n2s, 16 n2b
#define RP(i) ((const float*)d_in[3 + (i)])
#define CP(i) ((const float*)d_in[20 + (i)])

    float* x1     = ws;                            // 2 SZ
    float* ff2    = ws + 2 * (size_t)SZc;          // 2 SZ
    float* statsB = ws + 4 * (size_t)SZc;          // 16384 floats
    __half2* Wpk  = (__half2*)(statsB + 16384);    // 2048 used, 4096 reserved
    bf16* bfbase  = (bf16*)(Wpk + 4096);
    bf16* qkvb  = bfbase;                          // 6 SZ
    bf16* embRb = qkvb + 6 * (size_t)SZc;          // SZ
    bf16* embCb = embRb + SZc;                     // SZ
    bf16* attnb = embCb + SZc;                     // 2 SZ
    bf16* ffh   = attnb + 2 * (size_t)SZc;         // 4 SZ
    bf16* WT    = ffh + 4 * (size_t)SZc;           // 2 SZ
    short* costH  = (short*)(WT + 2 * (size_t)WHALF);  // 1 SZ halves
    short* costHT = costH + SZc;                       // 1 SZ halves
    float* stats1 = statsB;
    float* stats2 = statsB + 8192;

    setup_kernel<<<dim3(256, 18), 256, 0, stream>>>(
        row_emb, col_emb, embRb, embCb, statsB,
        cost, costH, costHT,
        RP(0), RP(1), RP(2), RP(7), RP(11), RP(13),
        CP(0), CP(1), CP(2), CP(7), CP(11), CP(13),
        RP(3), RP(4), RP(5), CP(3), CP(4), CP(5), Wpk, WT);
    k_qkv0<<<384, 256, 0, stream>>>(
        (const short*)embRb, (const short*)embCb, (const short*)WT, qkvb);
    k_attn0_qkv1<<<2432, 256, 0, stream>>>(
        (const short*)qkvb, costH, costHT, Wpk, RP(6), CP(6), attnb,
        (const short*)embRb, (const short*)embCb, (const short*)WT, qkvb);
    k_attn1_cat0<<<2176, 256, 0, stream>>>(
        (const short*)qkvb, costH, costHT, Wpk, RP(6), CP(6), attnb,
        (const short*)WT, RP(8), CP(8), row_emb, col_emb, x1, stats1);
    k_ff1n0_cat1<<<384, 256, 0, stream>>>(
        x1, stats1, RP(9), RP(10), CP(9), CP(10),
        (const short*)WT, RP(12), CP(12), ffh,
        (const short*)attnb, RP(8), CP(8), row_emb, col_emb, x1, stats1);
    k_ff2n0_ff1n1<<<384, 256, 0, stream>>>(
        (const short*)ffh, (const short*)WT, RP(14), CP(14),
        x1, stats1, RP(9), RP(10), CP(9), CP(10), ff2, stats2,
        RP(12), CP(12), ffh);
    k_ff2n1_apply0<<<640, 256, 0, stream>>>(
        (const short*)ffh, (const short*)WT, RP(14), CP(14),
        x1, stats1, RP(9), RP(10), CP(9), CP(10), ff2, stats2,
        RP(15), RP(16), CP(15), CP(16), out);
    k_apply1<<<512, 256, 0, stream>>>(
        ff2, stats2, RP(15), RP(16), CP(15), CP(16), out);
#undef RP
#undef CP
}

// Round 13
// 202.153 us; speedup vs baseline: 1.1249x; 1.1249x over previous
//
#include <hip/hip_runtime.h>
#include <hip/hip_bf16.h>
#include <hip/hip_fp16.h>

#define Bc 8
#define Nc 256
#define Dc 256
#define Hc 16
#define DKc 16
#define MSc 16
#define FFc 512
#define SZc 524288          // B*N*D elements
#define WHALF 524288        // bf16 elems of one half's 6 transposed weights
#define FFH 1048576         // B*N*FF elements

typedef __hip_bfloat16 bf16;
typedef __attribute__((ext_vector_type(8))) short bfrag8;   // 8 bf16 (4 VGPR)
typedef __attribute__((ext_vector_type(4))) float f32x4;    // MFMA acc

__device__ __forceinline__ short f2bs(float x) {
    bf16 t = __float2bfloat16(x);
    return *reinterpret_cast<short*>(&t);
}

// packed fp16 ReLU: no __half2 __hmax2 in ROCm 7.2 fp16 header; one VOP3P
// instruction, single 32-bit VGPR in/out (no pair-alignment pressure).
__device__ __forceinline__ __half2 pk_relu(__half2 x) {
    __half2 r;
    asm("v_pk_max_f16 %0, %1, 0" : "=v"(r) : "v"(x));
    return r;
}

// ---------------------------------------------------------------------------
// Dispatch 1: setup. grid (256, 15), block 256.
//  y=0/1: emb fp32->bf16 (8 elems/thread)
//  y=2:   x<64: zero stats; x=64/65: pack attn-MLP weights to __half2 table
//  y=3..14: weight transpose+convert W[K][N] fp32 -> WT[N][K] bf16
// ---------------------------------------------------------------------------
__global__ void setup_kernel(const float* __restrict__ e0, const float* __restrict__ e1,
                             bf16* __restrict__ o0, bf16* __restrict__ o1,
                             float* __restrict__ statsB,
                             const float* rWq, const float* rWk, const float* rWv,
                             const float* rcw, const float* rw1, const float* rw2,
                             const float* cWq, const float* cWk, const float* cWv,
                             const float* ccw, const float* cw1, const float* cw2,
                             const float* rm1w, const float* rm1b, const float* rm2w,
                             const float* cm1w, const float* cm1b, const float* cm2w,
                             __half2* __restrict__ Wpk,
                             bf16* __restrict__ WT) {
    int y = blockIdx.y;
    if (y < 2) {
        const float* src = y ? e1 : e0;
        bf16* dst = y ? o1 : o0;
        size_t base = (size_t)blockIdx.x * 2048 + threadIdx.x;
#pragma unroll
        for (int i = 0; i < 8; ++i)
            dst[base + i * 256] = __float2bfloat16(src[base + i * 256]);
        return;
    }
    if (y == 2) {
        if (blockIdx.x < 64) {
            statsB[blockIdx.x * 256 + threadIdx.x] = 0.f;
        } else if (blockIdx.x < 66) {
            // pack per-head MLP weights: [p][h][{wd,wc,wb,w2}][m] as half2
            int p = blockIdx.x - 64;
            const float* m1w = p ? cm1w : rm1w;
            const float* m1b = p ? cm1b : rm1b;
            const float* m2w = p ? cm2w : rm2w;
            int h = threadIdx.x >> 4, m = threadIdx.x & 15;
            __half2* wp = Wpk + (size_t)(p * 16 + h) * 64;
            wp[m]      = __float2half2_rn(m1w[h * 32 + m] * 0.25f);  // dot-scale folded
            wp[16 + m] = __float2half2_rn(m1w[h * 32 + 16 + m]);
            wp[32 + m] = __float2half2_rn(m1b[h * 16 + m]);
            wp[48 + m] = __float2half2_rn(m2w[h * 16 + m]);
        }
        return;
    }
    int z = y - 3;                    // 0..11
    int p = z / 6, widx = z % 6;
    const float* src; int K, N; size_t off;
    switch (widx) {
        case 0: src = p ? cWq : rWq; K = 256; N = 256; off = 0; break;
        case 1: src = p ? cWk : rWk; K = 256; N = 256; off = 65536; break;
        case 2: src = p ? cWv : rWv; K = 256; N = 256; off = 131072; break;
        case 3: src = p ? ccw : rcw; K = 256; N = 256; off = 196608; break;
        case 4: src = p ? cw1 : rw1; K = 256; N = 512; off = 262144; break;
        default: src = p ? cw2 : rw2; K = 512; N = 256; off = 393216; break;
    }
    int Ntiles = N >> 5, Ktiles = K >> 5;
    if ((int)blockIdx.x >= Ktiles * Ntiles) return;
    int kt = blockIdx.x / Ntiles, nt = blockIdx.x - kt * Ntiles;
    int k0 = kt * 32, n0 = nt * 32;
    bf16* dst = WT + (size_t)p * WHALF + off;
    __shared__ float t[32][33];
    int tx = threadIdx.x & 31, ty = threadIdx.x >> 5;   // 32 x 8
#pragma unroll
    for (int i = 0; i < 4; ++i)
        t[ty + i * 8][tx] = src[(size_t)(k0 + ty + i * 8) * N + n0 + tx];
    __syncthreads();
#pragma unroll
    for (int i = 0; i < 4; ++i)
        dst[(size_t)(n0 + ty + i * 8) * K + k0 + tx] = __float2bfloat16(t[tx][ty + i * 8]);
}

// ---------------------------------------------------------------------------
// Dispatch 2: QKV both halves. z = p*3 + j. Head-major bf16 out.
// R7: 2x2 wave tiling — each wave owns 32x32 (4 accs, 4 indep chains).
// grid (32, 4, 6).
// ---------------------------------------------------------------------------
__global__ void gemm_qkv_kernel(const short* __restrict__ embRb, const short* __restrict__ embCb,
                                const short* __restrict__ WT, bf16* __restrict__ qkv) {
    int z = blockIdx.z;
    int p = z / 3, j = z % 3;
    const short* A  = (j == 0) ? (p ? embCb : embRb) : (p ? embRb : embCb);
    const short* BT = WT + (size_t)p * WHALF + j * 65536;
    bf16* out = qkv + (size_t)z * SZc;

    int lane = threadIdx.x & 63, w = threadIdx.x >> 6;
    int m_base = blockIdx.x * 64 + (w & 1) * 32;
    int n_base = blockIdx.y * 64 + (w >> 1) * 32;
    int mr = lane & 15, quad = lane >> 4;

    const short* pa0 = A + (size_t)(m_base + mr) * 256 + quad * 8;
    const short* pa1 = pa0 + 16 * 256;
    const short* pb0 = BT + (size_t)(n_base + mr) * 256 + quad * 8;
    const short* pb1 = pb0 + 16 * 256;

    f32x4 acc00 = {0.f, 0.f, 0.f, 0.f}, acc01 = {0.f, 0.f, 0.f, 0.f};
    f32x4 acc10 = {0.f, 0.f, 0.f, 0.f}, acc11 = {0.f, 0.f, 0.f, 0.f};
#pragma unroll
    for (int kt = 0; kt < 256; kt += 32) {
        bfrag8 A0 = *(const bfrag8*)(pa0 + kt);
        bfrag8 A1 = *(const bfrag8*)(pa1 + kt);
        bfrag8 B0 = *(const bfrag8*)(pb0 + kt);
        bfrag8 B1 = *(const bfrag8*)(pb1 + kt);
        acc00 = __builtin_amdgcn_mfma_f32_16x16x32_bf16(A0, B0, acc00, 0, 0, 0);
        acc01 = __builtin_amdgcn_mfma_f32_16x16x32_bf16(A0, B1, acc01, 0, 0, 0);
        acc10 = __builtin_amdgcn_mfma_f32_16x16x32_bf16(A1, B0, acc10, 0, 0, 0);
        acc11 = __builtin_amdgcn_mfma_f32_16x16x32_bf16(A1, B1, acc11, 0, 0, 0);
    }

#pragma unroll
    for (int jt = 0; jt < 2; ++jt) {
        int col = n_base + jt * 16 + mr;
        int h = col >> 4, dk = col & 15;
        f32x4 a0 = jt ? acc01 : acc00;
        f32x4 a1 = jt ? acc11 : acc10;
#pragma unroll
        for (int r = 0; r < 4; ++r) {
            int row0 = m_base + quad * 4 + r;
            int row1 = row0 + 16;
            int b0 = row0 >> 8, n0 = row0 & 255;
            int b1 = row1 >> 8, n1 = row1 & 255;
            out[((size_t)(b0 * Hc + h) * Nc + n0) * DKc + dk] = __float2bfloat16(a0[r]);
            out[((size_t)(b1 * Hc + h) * Nc + n1) * DKc + dk] = __float2bfloat16(a1[r]);
        }
    }
}

// ---------------------------------------------------------------------------
// Dispatch 3: fused attention, both halves. grid (B, H, 32).
// R2: QK^T via MFMA; R4: packed-fp16 MLP; R5: bf16 qkv + SGPR weights.
// (R13: restored R8 structure — measured best at 204.5 µs.)
// ---------------------------------------------------------------------------
__global__ void attn_kernel(const short* __restrict__ qkv, const float* __restrict__ cost,
                            const __half2* __restrict__ Wpk,
                            const float* rm2b, const float* cm2b,
                            bf16* __restrict__ attnb) {
    int b = blockIdx.x, h = blockIdx.y;
    int p = blockIdx.z >> 4, rc = blockIdx.z & 15;
    const short* Q = qkv + (size_t)(p * 3 + 0) * SZc;
    const short* K = qkv + (size_t)(p * 3 + 1) * SZc;
    const short* V = qkv + (size_t)(p * 3 + 2) * SZc;
    const __half2* wp = Wpk + (size_t)(p * 16 + h) * 64;
    float b2v = (p ? cm2b : rm2b)[h];
    bf16* out_concat = attnb + (size_t)p * SZc;

    int bh = b * Hc + h;
    int r0 = rc * 16;
    int c = threadIdx.x;
    int lane = c & 63, wid = c >> 6;
    int mr = lane & 15, quad = lane >> 4;

    __shared__ __align__(16) short sVT[16 * 264];
    __shared__ __align__(16) short sEb[16 * 264];
    __shared__ float sPart[4 * 256];
    __shared__ float sSum[16 * 4];

    // V staging: thread c owns V row c (col c of V^T) — already bf16
    {
        const short* vp = V + ((size_t)bh * Nc + c) * DKc;
        bfrag8 v0 = *(const bfrag8*)vp;
        bfrag8 v1 = *(const bfrag8*)(vp + 8);
#pragma unroll
        for (int i = 0; i < 8; ++i) {
            sVT[i * 264 + c]       = v0[i];
            sVT[(8 + i) * 264 + c] = v1[i];
        }
    }

    // --- scores via MFMA: S(16 x 256) = Q(16x16) . K^T, 4 tiles per wave ---
    bfrag8 qf = {0, 0, 0, 0, 0, 0, 0, 0};
    if (quad < 2)
        qf = *(const bfrag8*)(Q + ((size_t)bh * Nc + r0 + mr) * DKc + quad * 8);

    // raw dot (0.25 scale folded into wp[0..15]), packed as half2 (s, s+1)
    __half2 sv2[8];
#pragma unroll
    for (int t = 0; t < 4; ++t) {
        bfrag8 kf = {0, 0, 0, 0, 0, 0, 0, 0};
        if (quad < 2)
            kf = *(const bfrag8*)(K + ((size_t)bh * Nc + wid * 64 + t * 16 + mr) * DKc + quad * 8);
        f32x4 acc = {0.f, 0.f, 0.f, 0.f};
        acc = __builtin_amdgcn_mfma_f32_16x16x32_bf16(qf, kf, acc, 0, 0, 0);
        sv2[t * 2]     = __floats2half2_rn(acc[0], acc[1]);
        sv2[t * 2 + 1] = __floats2half2_rn(acc[2], acc[3]);
    }

    // --- cost values for this lane's 16 (row, col) pairs, packed half2 ---
    const float* costR = cost + (size_t)b * Nc * Nc;
    __half2 cv2[8];
    if (p) {
        // transposed access: cost'[r][c] = cost[c][r] -> float4 along r
#pragma unroll
        for (int t = 0; t < 4; ++t) {
            float4 cvv = *(const float4*)(costR +
                (size_t)(wid * 64 + t * 16 + mr) * Nc + r0 + quad * 4);
            cv2[t * 2]     = __floats2half2_rn(cvv.x, cvv.y);
            cv2[t * 2 + 1] = __floats2half2_rn(cvv.z, cvv.w);
        }
    } else {
#pragma unroll
        for (int t = 0; t < 4; ++t) {
            float c0 = costR[(size_t)(r0 + quad * 4 + 0) * Nc + wid * 64 + t * 16 + mr];
            float c1 = costR[(size_t)(r0 + quad * 4 + 1) * Nc + wid * 64 + t * 16 + mr];
            float c2 = costR[(size_t)(r0 + quad * 4 + 2) * Nc + wid * 64 + t * 16 + mr];
            float c3 = costR[(size_t)(r0 + quad * 4 + 3) * Nc + wid * 64 + t * 16 + mr];
            cv2[t * 2]     = __floats2half2_rn(c0, c1);
            cv2[t * 2 + 1] = __floats2half2_rn(c2, c3);
        }
    }

    __syncthreads();   // sVT staged

    // --- 2->16->1 MLP, m-outer, packed fp16; weights SGPR-resident ---
    const __half2 z2 = __half2half2(__float2half(0.f));
    __half2 mix2[8] = {z2, z2, z2, z2, z2, z2, z2, z2};
#pragma unroll
    for (int m = 0; m < MSc; ++m) {
        __half2 w1d = wp[m];
        __half2 w1c = wp[16 + m];
        __half2 b1v = wp[32 + m];
        __half2 w2v = wp[48 + m];
#pragma unroll
        for (int s = 0; s < 8; ++s) {
            __half2 tt = __hfma2(sv2[s], w1d, __hfma2(cv2[s], w1c, b1v));
            mix2[s] = __hfma2(pk_relu(tt), w2v, mix2[s]);
        }
    }
    float ex[16];
#pragma unroll
    for (int s = 0; s < 8; ++s) {
        float2 mf = __half22float2(mix2[s]);
        ex[s * 2]     = __expf(mf.x + b2v);
        ex[s * 2 + 1] = __expf(mf.y + b2v);
    }

    // write P (unnormalized) to LDS for the PV MFMA (s index = t*4+r)
#pragma unroll
    for (int t = 0; t < 4; ++t)
#pragma unroll
        for (int r = 0; r < 4; ++r)
            sEb[(quad * 4 + r) * 264 + wid * 64 + t * 16 + mr] = f2bs(ex[t * 4 + r]);

    // row sums: shfl_xor over lane bits 0..3 reduces the 16 cols in quad group
#pragma unroll
    for (int r = 0; r < 4; ++r) {
        float rp = ex[r] + ex[4 + r] + ex[8 + r] + ex[12 + r];
        rp += __shfl_xor(rp, 1);
        rp += __shfl_xor(rp, 2);
        rp += __shfl_xor(rp, 4);
        rp += __shfl_xor(rp, 8);
        if (mr == 0) sSum[(quad * 4 + r) * 4 + wid] = rp;
    }
    __syncthreads();

    {
        const short* pa = &sEb[mr * 264 + wid * 64 + quad * 8];
        const short* pb = &sVT[mr * 264 + wid * 64 + quad * 8];
        f32x4 acc = {0.f, 0.f, 0.f, 0.f};
        bfrag8 a0 = *(const bfrag8*)pa;
        bfrag8 b0 = *(const bfrag8*)pb;
        acc = __builtin_amdgcn_mfma_f32_16x16x32_bf16(a0, b0, acc, 0, 0, 0);
        bfrag8 a1 = *(const bfrag8*)(pa + 32);
        bfrag8 b1 = *(const bfrag8*)(pb + 32);
        acc = __builtin_amdgcn_mfma_f32_16x16x32_bf16(a1, b1, acc, 0, 0, 0);
#pragma unroll
        for (int r = 0; r < 4; ++r)
            sPart[wid * 256 + (quad * 4 + r) * 16 + mr] = acc[r];
    }
    __syncthreads();

    {
        int r = c >> 4, dk = c & 15;
        float o = sPart[c] + sPart[256 + c] + sPart[512 + c] + sPart[768 + c];
        float sum = sSum[r * 4] + sSum[r * 4 + 1] + sSum[r * 4 + 2] + sSum[r * 4 + 3];
        out_concat[((size_t)(b * Nc + r0 + r)) * Dc + h * DKc + dk] =
            __float2bfloat16(o / sum);
    }
}

// ---------------------------------------------------------------------------
// Dispatch 4: concat GEMM + bias + residual + stats1 atomics.
// R8: 2x2 wave tiling (32x32/wave). grid (32, 4, 2).
// ---------------------------------------------------------------------------
__global__ void gemm_cat_kernel(const short* __restrict__ attnb, const short* __restrict__ WT,
                                const float* rcb, const float* ccb,
                                const float* __restrict__ resR, const float* __restrict__ resC,
                                float* __restrict__ x1, float* __restrict__ stats1) {
    int p = blockIdx.z;
    const short* A  = attnb + (size_t)p * SZc;
    const short* BT = WT + (size_t)p * WHALF + 196608;
    const float* bias = p ? ccb : rcb;
    const float* res  = p ? resC : resR;
    float* outF = x1 + (size_t)p * SZc;
    float* st   = stats1 + p * 4096;

    int lane = threadIdx.x & 63, w = threadIdx.x >> 6;
    int m_base = blockIdx.x * 64 + (w & 1) * 32;
    int n_base = blockIdx.y * 64 + (w >> 1) * 32;
    int mr = lane & 15, quad = lane >> 4;

    const short* pa0 = A + (size_t)(m_base + mr) * 256 + quad * 8;
    const short* pa1 = pa0 + (size_t)16 * 256;
    const short* pb0 = BT + (size_t)(n_base + mr) * 256 + quad * 8;
    const short* pb1 = pb0 + (size_t)16 * 256;

    f32x4 acc00 = {0.f, 0.f, 0.f, 0.f}, acc01 = {0.f, 0.f, 0.f, 0.f};
    f32x4 acc10 = {0.f, 0.f, 0.f, 0.f}, acc11 = {0.f, 0.f, 0.f, 0.f};
#pragma unroll
    for (int kt = 0; kt < 256; kt += 32) {
        bfrag8 A0 = *(const bfrag8*)(pa0 + kt);
        bfrag8 A1 = *(const bfrag8*)(pa1 + kt);
        bfrag8 B0 = *(const bfrag8*)(pb0 + kt);
        bfrag8 B1 = *(const bfrag8*)(pb1 + kt);
        acc00 = __builtin_amdgcn_mfma_f32_16x16x32_bf16(A0, B0, acc00, 0, 0, 0);
        acc01 = __builtin_amdgcn_mfma_f32_16x16x32_bf16(A0, B1, acc01, 0, 0, 0);
        acc10 = __builtin_amdgcn_mfma_f32_16x16x32_bf16(A1, B0, acc10, 0, 0, 0);
        acc11 = __builtin_amdgcn_mfma_f32_16x16x32_bf16(A1, B1, acc11, 0, 0, 0);
    }

    int bb = m_base >> 8;
#pragma unroll
    for (int jt = 0; jt < 2; ++jt) {
        int col = n_base + jt * 16 + mr;
        float bv = bias[col];
        f32x4 a0 = jt ? acc01 : acc00;
        f32x4 a1 = jt ? acc11 : acc10;
        float ssum = 0.f, ssq = 0.f;
#pragma unroll
        for (int r = 0; r < 4; ++r) {
            int row0 = m_base + quad * 4 + r;
            int row1 = row0 + 16;
            float v0 = a0[r] + bv + res[(size_t)row0 * 256 + col];
            float v1 = a1[r] + bv + res[(size_t)row1 * 256 + col];
            outF[(size_t)row0 * 256 + col] = v0;
            outF[(size_t)row1 * 256 + col] = v1;
            ssum += v0 + v1;
            ssq  += v0 * v0 + v1 * v1;
        }
        atomicAdd(&st[(bb * 256 + col) * 2],     ssum);
        atomicAdd(&st[(bb * 256 + col) * 2 + 1], ssq);
    }
}

// ---------------------------------------------------------------------------
// Dispatch 5: FF1 with on-the-fly norm1 of A (fused). 2x2 tiling. grid (32,8,2).
// ---------------------------------------------------------------------------
__global__ __launch_bounds__(256) void gemm_ff1n_kernel(
        const float* __restrict__ x1, const float* __restrict__ stats1,
        const float* rn1s, const float* rn1b, const float* cn1s, const float* cn1b,
        const short* __restrict__ WT, const float* rb1, const float* cb1,
        bf16* __restrict__ ffh) {
    int p = blockIdx.z;
    const float* X   = x1 + (size_t)p * SZc;
    const float* st  = stats1 + p * 4096;
    const float* n1s = p ? cn1s : rn1s;
    const float* n1b = p ? cn1b : rn1b;
    const short* BT  = WT + (size_t)p * WHALF + 262144;
    const float* bias = p ? cb1 : rb1;
    bf16* outB = ffh + (size_t)p * FFH;

    __shared__ __align__(16) short sA[64 * 264];
    int c = threadIdx.x;
    int m_base = blockIdx.x * 64;
    int b = m_base >> 8;

    // per-thread column-c norm constants
    float s = st[(b * 256 + c) * 2];
    float q = st[(b * 256 + c) * 2 + 1];
    float mean = s * (1.f / Nc);
    float var = q * (1.f / Nc) - mean * mean;
    float inv = rsqrtf(var + 1e-5f) * n1s[c];
    float nb = n1b[c];
#pragma unroll 8
    for (int i = 0; i < 64; ++i) {
        float v = X[(size_t)(m_base + i) * 256 + c];
        sA[i * 264 + c] = f2bs((v - mean) * inv + nb);
    }
    __syncthreads();

    int lane = c & 63, w = c >> 6;
    int mloc = (w & 1) * 32;
    int n_base = blockIdx.y * 64 + (w >> 1) * 32;
    int mr = lane & 15, quad = lane >> 4;

    const short* pa0 = &sA[(mloc + mr) * 264 + quad * 8];
    const short* pa1 = pa0 + 16 * 264;
    const short* pb0 = BT + (size_t)(n_base + mr) * 256 + quad * 8;
    const short* pb1 = pb0 + 16 * 256;

    f32x4 acc00 = {0.f, 0.f, 0.f, 0.f}, acc01 = {0.f, 0.f, 0.f, 0.f};
    f32x4 acc10 = {0.f, 0.f, 0.f, 0.f}, acc11 = {0.f, 0.f, 0.f, 0.f};
#pragma unroll
    for (int kt = 0; kt < 256; kt += 32) {
        bfrag8 A0 = *(const bfrag8*)(pa0 + kt);
        bfrag8 A1 = *(const bfrag8*)(pa1 + kt);
        bfrag8 B0 = *(const bfrag8*)(pb0 + kt);
        bfrag8 B1 = *(const bfrag8*)(pb1 + kt);
        acc00 = __builtin_amdgcn_mfma_f32_16x16x32_bf16(A0, B0, acc00, 0, 0, 0);
        acc01 = __builtin_amdgcn_mfma_f32_16x16x32_bf16(A0, B1, acc01, 0, 0, 0);
        acc10 = __builtin_amdgcn_mfma_f32_16x16x32_bf16(A1, B0, acc10, 0, 0, 0);
        acc11 = __builtin_amdgcn_mfma_f32_16x16x32_bf16(A1, B1, acc11, 0, 0, 0);
    }

#pragma unroll
    for (int jt = 0; jt < 2; ++jt) {
        int col = n_base + jt * 16 + mr;
        float bv = bias[col];
        f32x4 a0 = jt ? acc01 : acc00;
        f32x4 a1 = jt ? acc11 : acc10;
#pragma unroll
        for (int r = 0; r < 4; ++r) {
            int row0 = m_base + mloc + quad * 4 + r;
            int row1 = row0 + 16;
            outB[(size_t)row0 * 512 + col] = __float2bfloat16(fmaxf(a0[r] + bv, 0.f));
            outB[(size_t)row1 * 512 + col] = __float2bfloat16(fmaxf(a1[r] + bv, 0.f));
        }
    }
}

// ---------------------------------------------------------------------------
// Dispatch 6: FF2 + recomputed norm1 residual + stats2 atomics.
// R8: 2x2 wave tiling (32x32/wave). grid (32, 4, 2).
// ---------------------------------------------------------------------------
__global__ void gemm_ff2n_kernel(const short* __restrict__ ffh, const short* __restrict__ WT,
                                 const float* rb2, const float* cb2,
                                 const float* __restrict__ x1, const float* __restrict__ stats1,
                                 const float* rn1s, const float* rn1b,
                                 const float* cn1s, const float* cn1b,
                                 float* __restrict__ ff2, float* __restrict__ stats2) {
    int p = blockIdx.z;
    const short* A  = ffh + (size_t)p * FFH;
    const short* BT = WT + (size_t)p * WHALF + 393216;
    const float* bias = p ? cb2 : rb2;
    const float* X   = x1 + (size_t)p * SZc;
    const float* st1 = stats1 + p * 4096;
    const float* n1s = p ? cn1s : rn1s;
    const float* n1b = p ? cn1b : rn1b;
    float* outF = ff2 + (size_t)p * SZc;
    float* st2  = stats2 + p * 4096;

    int lane = threadIdx.x & 63, w = threadIdx.x >> 6;
    int m_base = blockIdx.x * 64 + (w & 1) * 32;
    int n_base = blockIdx.y * 64 + (w >> 1) * 32;
    int mr = lane & 15, quad = lane >> 4;

    const short* pa0 = A + (size_t)(m_base + mr) * 512 + quad * 8;
    const short* pa1 = pa0 + (size_t)16 * 512;
    const short* pb0 = BT + (size_t)(n_base + mr) * 512 + quad * 8;
    const short* pb1 = pb0 + (size_t)16 * 512;

    f32x4 acc00 = {0.f, 0.f, 0.f, 0.f}, acc01 = {0.f, 0.f, 0.f, 0.f};
    f32x4 acc10 = {0.f, 0.f, 0.f, 0.f}, acc11 = {0.f, 0.f, 0.f, 0.f};
#pragma unroll
    for (int kt = 0; kt < 512; kt += 32) {
        bfrag8 A0 = *(const bfrag8*)(pa0 + kt);
        bfrag8 A1 = *(const bfrag8*)(pa1 + kt);
        bfrag8 B0 = *(const bfrag8*)(pb0 + kt);
        bfrag8 B1 = *(const bfrag8*)(pb1 + kt);
        acc00 = __builtin_amdgcn_mfma_f32_16x16x32_bf16(A0, B0, acc00, 0, 0, 0);
        acc01 = __builtin_amdgcn_mfma_f32_16x16x32_bf16(A0, B1, acc01, 0, 0, 0);
        acc10 = __builtin_amdgcn_mfma_f32_16x16x32_bf16(A1, B0, acc10, 0, 0, 0);
        acc11 = __builtin_amdgcn_mfma_f32_16x16x32_bf16(A1, B1, acc11, 0, 0, 0);
    }

    int bb = m_base >> 8;
#pragma unroll
    for (int jt = 0; jt < 2; ++jt) {
        int col = n_base + jt * 16 + mr;
        // norm1 constants for this column
        float s1 = st1[(bb * 256 + col) * 2];
        float q1 = st1[(bb * 256 + col) * 2 + 1];
        float mean1 = s1 * (1.f / Nc);
        float var1 = q1 * (1.f / Nc) - mean1 * mean1;
        float inv1 = rsqrtf(var1 + 1e-5f) * n1s[col];
        float nb1 = n1b[col];
        float bv = bias[col];
        f32x4 a0 = jt ? acc01 : acc00;
        f32x4 a1 = jt ? acc11 : acc10;
        float ssum = 0.f, ssq = 0.f;
#pragma unroll
        for (int r = 0; r < 4; ++r) {
            int row0 = m_base + quad * 4 + r;
            int row1 = row0 + 16;
            float res0 = (X[(size_t)row0 * 256 + col] - mean1) * inv1 + nb1;
            float res1 = (X[(size_t)row1 * 256 + col] - mean1) * inv1 + nb1;
            float v0 = a0[r] + bv + res0;
            float v1 = a1[r] + bv + res1;
            outF[(size_t)row0 * 256 + col] = v0;
            outF[(size_t)row1 * 256 + col] = v1;
            ssum += v0 + v1;
            ssq  += v0 * v0 + v1 * v1;
        }
        atomicAdd(&st2[(bb * 256 + col) * 2],     ssum);
        atomicAdd(&st2[(bb * 256 + col) * 2 + 1], ssq);
    }
}

// ---------------------------------------------------------------------------
// Dispatch 7: final norm2 apply -> output. grid (512, 2), float4, 4 rows/blk.
// ---------------------------------------------------------------------------
__global__ void apply_kernel(const float* __restrict__ x, const float* __restrict__ stats,
                             const float* sR, const float* bR,
                             const float* sC, const float* bC,
                             float* __restrict__ outF) {
    int p = blockIdx.y;
    int t = threadIdx.x;
    int row = blockIdx.x * 4 + (t >> 6);
    int d0 = (t & 63) * 4;
    int b = row >> 8;
    const float* st = stats + p * 4096 + (size_t)(b * 256 + d0) * 2;
    float4 s01 = *(const float4*)st;         // sum0,sq0,sum1,sq1
    float4 s23 = *(const float4*)(st + 4);   // sum2,sq2,sum3,sq3
    const float* sp = p ? sC : sR;
    const float* bp = p ? bC : bR;
    float4 sc = *(const float4*)(sp + d0);
    float4 bi = *(const float4*)(bp + d0);
    float4 v = *(const float4*)(x + (size_t)p * SZc + (size_t)row * Dc + d0);
    float sums[4] = {s01.x, s01.z, s23.x, s23.z};
    float sqs[4]  = {s01.y, s01.w, s23.y, s23.w};
    float vv[4]   = {v.x, v.y, v.z, v.w};
    float scs[4]  = {sc.x, sc.y, sc.z, sc.w};
    float bis[4]  = {bi.x, bi.y, bi.z, bi.w};
    float4 o;
#pragma unroll
    for (int j = 0; j < 4; ++j) {
        float mean = sums[j] * (1.f / Nc);
        float var = sqs[j] * (1.f / Nc) - mean * mean;
        float inv = rsqrtf(var + 1e-5f);
        ((float*)&o)[j] = (vv[j] - mean) * inv * scs[j] + bis[j];
    }
    *(float4*)(outF + (size_t)p * SZc + (size_t)row * Dc + d0) = o;
}

extern "C" void kernel_launch(void* const* d_in, const int* in_sizes, int n_in,
                              void* d_out, int out_size, void* d_ws, size_t ws_size,
                              hipStream_t stream) {
    const float* row_emb = (const float*)d_in[0];
    const float* col_emb = (const float*)d_in[1];
    const float* cost    = (const float*)d_in[2];
    float* out = (float*)d_out;
    float* ws = (float*)d_ws;
    // per-half param index (dict order): 0 Wq, 1 Wk, 2 Wv, 3 m1w, 4 m1b,
    // 5 m2w, 6 m2b, 7 cw, 8 cb, 9 n1s, 10 n1b, 11 w1, 12 b1, 13 w2, 14 b2,
    // 15 n2s, 16 n2b
#define RP(i) ((const float*)d_in[3 + (i)])
#define CP(i) ((const float*)d_in[20 + (i)])

    float* x1     = ws;                            // 2 SZ
    float* ff2    = ws + 2 * (size_t)SZc;          // 2 SZ
    float* statsB = ws + 4 * (size_t)SZc;          // 16384 floats
    __half2* Wpk  = (__half2*)(statsB + 16384);    // 2048 used, 4096 reserved
    bf16* bfbase  = (bf16*)(Wpk + 4096);
    bf16* qkvb  = bfbase;                          // 6 SZ
    bf16* embRb = qkvb + 6 * (size_t)SZc;          // SZ
    bf16* embCb = embRb + SZc;                     // SZ
    bf16* attnb = embCb + SZc;                     // 2 SZ
    bf16* ffh   = attnb + 2 * (size_t)SZc;         // 4 SZ
    bf16* WT    = ffh + 4 * (size_t)SZc;           // 2 SZ
    float* stats1 = statsB;
    float* stats2 = statsB + 8192;

    setup_kernel<<<dim3(256, 15), 256, 0, stream>>>(
        row_emb, col_emb, embRb, embCb, statsB,
        RP(0), RP(1), RP(2), RP(7), RP(11), RP(13),
        CP(0), CP(1), CP(2), CP(7), CP(11), CP(13),
        RP(3), RP(4), RP(5), CP(3), CP(4), CP(5), Wpk, WT);
    gemm_qkv_kernel<<<dim3(32, 4, 6), 256, 0, stream>>>(
        (const short*)embRb, (const short*)embCb, (const short*)WT, qkvb);
    attn_kernel<<<dim3(Bc, Hc, 32), 256, 0, stream>>>(
        (const short*)qkvb, cost, Wpk, RP(6), CP(6), attnb);
    gemm_cat_kernel<<<dim3(32, 4, 2), 256, 0, stream>>>(
        (const short*)attnb, (const short*)WT, RP(8), CP(8), row_emb, col_emb, x1, stats1);
    gemm_ff1n_kernel<<<dim3(32, 8, 2), 256, 0, stream>>>(
        x1, stats1, RP(9), RP(10), CP(9), CP(10),
        (const short*)WT, RP(12), CP(12), ffh);
    gemm_ff2n_kernel<<<dim3(32, 4, 2), 256, 0, stream>>>(
        (const short*)ffh, (const short*)WT, RP(14), CP(14),
        x1, stats1, RP(9), RP(10), CP(9), CP(10), ff2, stats2);
    apply_kernel<<<dim3(512, 2), 256, 0, stream>>>(
        ff2, stats2, RP(15), RP(16), CP(15), CP(16), out);
#undef RP
#undef CP
}